// Round 1
// baseline (322.042 us; speedup 1.0000x reference)
//
#include <hip/hip_runtime.h>

// Guided-filter detail branch, fully fused single kernel.
// out = x_norm - (box(a)*g + box(b)), a,b from per-channel guided filter stats,
// all 17x17 box filters (zero-padded window sum / 289).
//
// Per block: 32x32 output tile.
//   F-region (fields, 64x64)  = tile + 2*2R halo
//   A-region (a/b,   48x48)   = tile + 2R halo
// All box filters are separable sliding-window sums in LDS.

constexpr int R  = 8;
constexpr int K  = 17;            // 2R+1
constexpr int TO = 32;            // output tile side
constexpr int RF = 64;            // field region side = TO + 4R
constexpr int FS = 65;            // field plane row stride (padded)
constexpr int HS = 49;            // hbox plane stride (48 cols + 1)
constexpr int AS = 49;            // a/b plane stride  (48 cols + 1)
constexpr int H2S = 33;           // hbox2 plane stride (32 cols + 1)

__global__ __launch_bounds__(512)
void guided_detail_kernel(const float* __restrict__ x, float* __restrict__ out,
                          int B, int H, int W) {
  // LDS layout (floats):
  //  g0,g1,g2,gray : 4 planes 64x65          = 16640
  //  hb0,hb1,hb2   : 3 planes 64x49          =  9408  (reused for hbox2 48x33)
  //  mi            : 48x49                   =  2352
  //  ap,bp         : 2 planes 48x49          =  4704
  __shared__ float lds[33104];                // 132,416 B
  float* const g0  = lds;
  float* const g1  = lds + 4160;
  float* const g2  = lds + 8320;
  float* const gry = lds + 12480;
  float* const hb0 = lds + 16640;
  float* const hb1 = lds + 19776;
  float* const hb2 = lds + 22912;
  float* const mi  = lds + 26048;
  float* const ap  = lds + 28400;
  float* const bp  = lds + 30752;

  constexpr float AREA_INV = 1.0f / 289.0f;
  constexpr float EPS = 0.001f;

  const int tid = threadIdx.x;
  const int tilesX = W / TO;
  const int tilesY = H / TO;
  const int tilesPer = tilesX * tilesY;
  const int b   = blockIdx.x / tilesPer;
  const int t   = blockIdx.x % tilesPer;
  const int ty0 = (t / tilesX) * TO;
  const int tx0 = (t % tilesX) * TO;
  const int fy0 = ty0 - 2 * R;
  const int fx0 = tx0 - 2 * R;

  const size_t plane = (size_t)H * W;
  const float* xb = x + (size_t)b * 3 * plane;

  // ---------- phase 0: load F-region, normalize+clip, gray ----------
  for (int idx = tid; idx < RF * RF; idx += 512) {
    const int ry = idx >> 6;
    const int rx = idx & 63;
    const int gy = fy0 + ry;
    const int gx = fx0 + rx;
    float v0 = 0.f, v1 = 0.f, v2 = 0.f;
    if (gy >= 0 && gy < H && gx >= 0 && gx < W) {
      const size_t o = (size_t)gy * W + gx;
      v0 = fminf(fmaxf(xb[o]             * 0.229f + 0.485f, 0.f), 1.f);
      v1 = fminf(fmaxf(xb[o +   plane]   * 0.224f + 0.456f, 0.f), 1.f);
      v2 = fminf(fmaxf(xb[o + 2*plane]   * 0.225f + 0.406f, 0.f), 1.f);
    }
    const int l = ry * FS + rx;
    g0[l] = v0; g1[l] = v1; g2[l] = v2;
    gry[l] = (v0 + v1 + v2) * (1.f / 3.f);
  }
  __syncthreads();

  // ---------- mean_i = box(gray), channel-independent ----------
  { // horizontal: 64 rows x 8 col-groups of 6 outputs
    const int r  = tid >> 3;
    const int xg = tid & 7;
    const int xs = 6 * xg;
    float s = 0.f;
    #pragma unroll
    for (int k = 0; k < K; ++k) s += gry[r * FS + xs + k];
    #pragma unroll
    for (int j = 0; j < 6; ++j) {
      hb0[r * HS + xs + j] = s;
      if (j < 5) s += gry[r * FS + xs + K + j] - gry[r * FS + xs + j];
    }
  }
  __syncthreads();
  if (tid < 384) { // vertical: 48 cols x 8 row-groups of 6
    const int col = tid % 48;
    const int r0  = (tid / 48) * 6;
    float s = 0.f;
    #pragma unroll
    for (int k = 0; k < K; ++k) s += hb0[(r0 + k) * HS + col];
    #pragma unroll
    for (int j = 0; j < 6; ++j) {
      mi[(r0 + j) * AS + col] = s * AREA_INV;
      if (j < 5) s += hb0[(r0 + K + j) * HS + col] - hb0[(r0 + j) * HS + col];
    }
  }
  __syncthreads();

  // ---------- per channel ----------
  for (int c = 0; c < 3; ++c) {
    const float* const gc = (c == 0) ? g0 : (c == 1) ? g1 : g2;

    // hbox of {g, g*gray, g*g}: 64 rows x 8 groups x 6 outputs
    {
      const int r  = tid >> 3;
      const int xg = tid & 7;
      const int xs = 6 * xg;
      float sg = 0.f, si = 0.f, sq = 0.f;
      #pragma unroll
      for (int k = 0; k < K; ++k) {
        const float gv = gc[r * FS + xs + k];
        const float iv = gry[r * FS + xs + k];
        sg += gv; si += gv * iv; sq += gv * gv;
      }
      #pragma unroll
      for (int j = 0; j < 6; ++j) {
        hb0[r * HS + xs + j] = sg;
        hb1[r * HS + xs + j] = si;
        hb2[r * HS + xs + j] = sq;
        if (j < 5) {
          const float gn = gc[r * FS + xs + K + j], vn = gry[r * FS + xs + K + j];
          const float go = gc[r * FS + xs + j],     vo = gry[r * FS + xs + j];
          sg += gn - go;
          si += gn * vn - go * vo;
          sq += gn * gn - go * go;
        }
      }
    }
    __syncthreads();

    // vbox + a,b: 48 cols x 8 row-groups of 6 (A-region 48x48)
    if (tid < 384) {
      const int col = tid % 48;
      const int r0  = (tid / 48) * 6;
      float sg = 0.f, si = 0.f, sq = 0.f;
      #pragma unroll
      for (int k = 0; k < K; ++k) {
        sg += hb0[(r0 + k) * HS + col];
        si += hb1[(r0 + k) * HS + col];
        sq += hb2[(r0 + k) * HS + col];
      }
      #pragma unroll
      for (int j = 0; j < 6; ++j) {
        const int ar = r0 + j;
        const int gy = ty0 - R + ar;          // image coords of this a/b element
        const int gx = tx0 - R + col;
        float av = 0.f, bv = 0.f;
        if (gy >= 0 && gy < H && gx >= 0 && gx < W) {  // a,b zero-padded outside image
          const float mg  = sg * AREA_INV;
          const float mgi = si * AREA_INV;
          const float mgg = sq * AREA_INV;
          const float miv = mi[ar * AS + col];
          av = (mgi - mg * miv) / (mgg - mg * mg + EPS);
          bv = miv - av * mg;
        }
        ap[ar * AS + col] = av;
        bp[ar * AS + col] = bv;
        if (j < 5) {
          sg += hb0[(r0 + K + j) * HS + col] - hb0[(r0 + j) * HS + col];
          si += hb1[(r0 + K + j) * HS + col] - hb1[(r0 + j) * HS + col];
          sq += hb2[(r0 + K + j) * HS + col] - hb2[(r0 + j) * HS + col];
        }
      }
    }
    __syncthreads();

    // hbox2 of a,b (reuse hb0/hb1 with stride H2S): 48 rows x 8 groups x 4 outputs
    if (tid < 384) {
      const int r  = tid >> 3;
      const int xg = tid & 7;
      const int xs = 4 * xg;
      float sa = 0.f, sb = 0.f;
      #pragma unroll
      for (int k = 0; k < K; ++k) {
        sa += ap[r * AS + xs + k];
        sb += bp[r * AS + xs + k];
      }
      #pragma unroll
      for (int j = 0; j < 4; ++j) {
        hb0[r * H2S + xs + j] = sa;
        hb1[r * H2S + xs + j] = sb;
        if (j < 3) {
          sa += ap[r * AS + xs + K + j] - ap[r * AS + xs + j];
          sb += bp[r * AS + xs + K + j] - bp[r * AS + xs + j];
        }
      }
    }
    __syncthreads();

    // vbox2 + final combine + store: 32 cols x 16 row-groups of 2
    {
      const int col = tid & 31;
      const int r0  = (tid >> 5) * 2;
      float sa = 0.f, sb = 0.f;
      #pragma unroll
      for (int k = 0; k < K; ++k) {
        sa += hb0[(r0 + k) * H2S + col];
        sb += hb1[(r0 + k) * H2S + col];
      }
      #pragma unroll
      for (int j = 0; j < 2; ++j) {
        const int orow = r0 + j;
        const float gv = gc[(orow + 2 * R) * FS + (col + 2 * R)];
        const float res = gv - (sa * AREA_INV * gv + sb * AREA_INV);
        out[((size_t)b * 3 + c) * plane + (size_t)(ty0 + orow) * W + (tx0 + col)] = res;
        if (j < 1) {
          sa += hb0[(r0 + K) * H2S + col] - hb0[r0 * H2S + col];
          sb += hb1[(r0 + K) * H2S + col] - hb1[r0 * H2S + col];
        }
      }
    }
    __syncthreads();
  }
}

extern "C" void kernel_launch(void* const* d_in, const int* in_sizes, int n_in,
                              void* d_out, int out_size, void* d_ws, size_t ws_size,
                              hipStream_t stream) {
  const float* x = (const float*)d_in[0];
  float* out = (float*)d_out;
  const int H = 512, W = 512;
  const int B = in_sizes[0] / (3 * H * W);
  const int grid = B * (H / TO) * (W / TO);
  guided_detail_kernel<<<grid, 512, 0, stream>>>(x, out, B, H, W);
}